// Round 7
// baseline (98.374 us; speedup 1.0000x reference)
//
#include <hip/hip_runtime.h>
#include <hip/hip_bf16.h>

// Problem: B=8, N=4096, H=256, F=6
//   Wt[b][n][h] = sum_f osc[f][h][n] * sin(freq_f * t[b] + phase[f][n])
//   out[b][m][n] = sum_h x[b][m][h] * Wt[b][n][h]
//
// R7 (on the R6 winner: BK=64, LDS staging, reg prefetch):
//  - gemm: BM 64->32, grid 1024, LDS 41.5 KB -> 3 blocks/CU co-residency;
//    staggered block phases overlap barrier drains / epilogue writes with
//    other blocks' MFMA+loads. __launch_bounds__(512,6) caps VGPR at 85.
//  - build_w: 512 blocks (one 16-h slice each) instead of 64 -> all CUs busy.

#define B_  8
#define N_  4096
#define H_  256

typedef __attribute__((ext_vector_type(8))) short s8v;   // 8 bf16 (A/B frag)
typedef __attribute__((ext_vector_type(4))) float f4v;   // C/D frag

__global__ __launch_bounds__(256) void build_w(
    const float* __restrict__ osc,     // [6][256][256]  osc[f][h][n]
    const float* __restrict__ t,       // [8][1]
    const float* __restrict__ phase,   // [6][256]       phase[f][n]
    __hip_bfloat16* __restrict__ Wt)   // [8][256][256]  Wt[b][n][h]
{
    const float freqs[6] = {1.f, 2.f, 4.f, 8.f, 7.f, 5.f};
    __shared__ float tr[16 * 68];      // [hlocal][n], stride 68

    const int b  = blockIdx.z;
    const int n0 = blockIdx.y * 64;    // 4 n-tiles
    const int h0 = blockIdx.x * 16;    // 16 h-slices
    const int tid = threadIdx.x;

    const float tb = t[b];
    const int nr = (tid & 15) * 4;
    const int hr = tid >> 4;           // 0..15
    float s[6][4];
#pragma unroll
    for (int f = 0; f < 6; ++f)
#pragma unroll
        for (int j = 0; j < 4; ++j)
            s[f][j] = __sinf(freqs[f] * tb + phase[f * 256 + n0 + nr + j]);

    const int h = h0 + hr;
    float4 acc = make_float4(0.f, 0.f, 0.f, 0.f);
#pragma unroll
    for (int f = 0; f < 6; ++f) {
        float4 o = *(const float4*)&osc[f * 65536 + h * 256 + n0 + nr];
        acc.x += o.x * s[f][0];
        acc.y += o.y * s[f][1];
        acc.z += o.z * s[f][2];
        acc.w += o.w * s[f][3];
    }
    *(float4*)&tr[hr * 68 + nr] = acc;
    __syncthreads();

    // write: lane -> (n row nw, 4-wide h chunk hw), coalesced b64
    const int nw = tid >> 2;           // 0..63
    const int hw = (tid & 3) * 4;      // 0,4,8,12
    float v0 = tr[(hw + 0) * 68 + nw];
    float v1 = tr[(hw + 1) * 68 + nw];
    float v2 = tr[(hw + 2) * 68 + nw];
    float v3 = tr[(hw + 3) * 68 + nw];
    union { __hip_bfloat162 h2[2]; unsigned long long q; } cv;
    cv.h2[0] = __float22bfloat162_rn(make_float2(v0, v1));
    cv.h2[1] = __float22bfloat162_rn(make_float2(v2, v3));
    *(unsigned long long*)(Wt + (size_t)b * 65536 + (size_t)(n0 + nw) * 256 + h0 + hw) = cv.q;
}

// BK=64: LDS row stride 72 shorts (144 B), same aliasing class as R6 (clean).
#define LDST 72

__global__ __launch_bounds__(512, 6) void gemm(
    const float* __restrict__ X,              // [8][4096][256] fp32
    const __hip_bfloat16* __restrict__ Wt,    // [8][256][256]  bf16 [b][n][h]
    float* __restrict__ out)                  // [8][4096][256] fp32
{
    __shared__ short As[32 * LDST];           // As[m][k]   4.6 KB
    __shared__ short Bs[256 * LDST];          // Bs[n][k]  36.9 KB  (41.5 total -> 3 blk/CU)

    const int b     = blockIdx.y;
    const int mTile = blockIdx.x;             // 0..127, BM=32, BN=256

    const int tid    = threadIdx.x;
    const int lane   = tid & 63;
    const int wave   = tid >> 6;              // 0..7
    const int lane15 = lane & 15;
    const int quad   = lane >> 4;             // 0..3
    const int wm     = wave >> 2;             // 0..1: 16-row band
    const int wn     = wave & 3;              // 0..3: 64-col band

    const float* Xb          = X   + (size_t)b * N_ * H_ + (size_t)mTile * 32 * H_;
    const __hip_bfloat16* Wb = Wt  + (size_t)b * H_ * H_;
    float* Ob                = out + (size_t)b * N_ * H_ + (size_t)mTile * 32 * H_;

    // A staging: 32 rows x 64 k fp32 = 8 KB -> 1 float4/thread
    const int arow = tid >> 4;                // 0..31
    const int aseg = (tid & 15) * 4;          // 0..60
    const float* pa = Xb + (size_t)arow * H_ + aseg;

    // B staging: 256 rows x 64 k bf16 = 32 KB -> 32 shorts/thread (64 B contig)
    const int brow = tid >> 1;                // 0..255
    const int bhf  = (tid & 1) * 32;          // 0, 32
    const __hip_bfloat16* pb = Wb + (size_t)brow * H_ + bhf;

    f4v acc[4] = {};                          // 16 VGPRs

    // prefetch iter 0
    float4 av  = *(const float4*)pa;
    uint4  bv0 = *(const uint4*)(pb);
    uint4  bv1 = *(const uint4*)(pb + 8);
    uint4  bv2 = *(const uint4*)(pb + 16);
    uint4  bv3 = *(const uint4*)(pb + 24);

    for (int it = 0; it < 4; ++it) {
        // stage regs -> LDS (A converted fp32->bf16 in-register)
        union { __hip_bfloat162 h2[2]; unsigned long long q; } cv;
        cv.h2[0] = __float22bfloat162_rn(make_float2(av.x, av.y));
        cv.h2[1] = __float22bfloat162_rn(make_float2(av.z, av.w));
        *(unsigned long long*)(&As[arow * LDST + aseg]) = cv.q;
        *(uint4*)(&Bs[brow * LDST + bhf + 0])  = bv0;
        *(uint4*)(&Bs[brow * LDST + bhf + 8])  = bv1;
        *(uint4*)(&Bs[brow * LDST + bhf + 16]) = bv2;
        *(uint4*)(&Bs[brow * LDST + bhf + 24]) = bv3;
        __syncthreads();

        // prefetch iter+1 (overlaps the MFMA section)
        if (it < 3) {
            const int k = (it + 1) * 64;
            av  = *(const float4*)(pa + k);
            bv0 = *(const uint4*)(pb + k);
            bv1 = *(const uint4*)(pb + k + 8);
            bv2 = *(const uint4*)(pb + k + 16);
            bv3 = *(const uint4*)(pb + k + 24);
        }

        // two k-halves per iter: frag k = kh*32 + quad*8 + j
#pragma unroll
        for (int kh = 0; kh < 2; ++kh) {
            s8v af, bf[4];
            af = *(const s8v*)(&As[(wm * 16 + lane15) * LDST + kh * 32 + quad * 8]);
#pragma unroll
            for (int nt = 0; nt < 4; ++nt)
                bf[nt] = *(const s8v*)(&Bs[(wn * 64 + nt * 16 + lane15) * LDST + kh * 32 + quad * 8]);
#pragma unroll
            for (int nt = 0; nt < 4; ++nt)
                acc[nt] = __builtin_amdgcn_mfma_f32_16x16x32_bf16(
                    af, bf[nt], acc[nt], 0, 0, 0);
        }
        __syncthreads();
    }

    // epilogue: C/D layout col=lane15, row=quad*4+reg; nontemporal (write-once)
#pragma unroll
    for (int r = 0; r < 4; ++r) {
        int row = wm * 16 + quad * 4 + r;
        float* po = Ob + (size_t)row * H_ + wn * 64 + lane15;
#pragma unroll
        for (int nt = 0; nt < 4; ++nt)
            __builtin_nontemporal_store(acc[nt][r], po + nt * 16);
    }
}

extern "C" void kernel_launch(void* const* d_in, const int* in_sizes, int n_in,
                              void* d_out, int out_size, void* d_ws, size_t ws_size,
                              hipStream_t stream) {
    const float* x     = (const float*)d_in[0];   // [8][4096][256]
    const float* t     = (const float*)d_in[1];   // [8][1]
    const float* osc   = (const float*)d_in[2];   // [6][256][256]
    const float* phase = (const float*)d_in[3];   // [6][256]
    __hip_bfloat16* Wt = (__hip_bfloat16*)d_ws;   // 1 MB scratch, rebuilt every call
    float* out = (float*)d_out;

    dim3 gw(16, 4, 8);                            // (h-slice, n-tile, b) = 512 blocks
    build_w<<<gw, 256, 0, stream>>>(osc, t, phase, Wt);

    dim3 gg(128, 8);                              // (mTile, b) = 1024 blocks
    gemm<<<gg, 512, 0, stream>>>(x, Wt, out);
}

// Round 8
// 94.062 us; speedup vs baseline: 1.0458x; 1.0458x over previous
//
#include <hip/hip_runtime.h>
#include <hip/hip_bf16.h>

// Problem: B=8, N=4096, H=256, F=6
//   Wt[b][n][h] = sum_f osc[f][h][n] * sin(freq_f * t[b] + phase[f][n])
//   out[b][m][n] = sum_h x[b][m][h] * Wt[b][n][h]
//
// R8 = R6 base (BM=64, BN=256, BK=64, LDS staging, nontemporal stores)
//      + R7's 512-block build_w, plus:
//  - lightweight barrier: "s_waitcnt lgkmcnt(0); s_barrier" (asm, memory
//    clobber) instead of __syncthreads(). __syncthreads emits vmcnt(0)
//    before s_barrier, draining the prefetch loads every iteration — the
//    m97-plateau stall. LDS visibility only needs lgkmcnt; X/Wt are
//    read-only and out is epilogue-only, so skipping the vmcnt drain is
//    safe. Prefetched global loads now survive barriers (hipBLASLt style).
//  - depth-2 register prefetch: iter i+2's loads issue during iter i's
//    MFMA -> ~2 barrier periods of latency tolerance.

#define B_  8
#define N_  4096
#define H_  256

typedef __attribute__((ext_vector_type(8))) short s8v;   // 8 bf16 (A/B frag)
typedef __attribute__((ext_vector_type(4))) float f4v;   // C/D frag

// LDS-only barrier: no vmcnt drain (safe: no cross-wave global hazards).
#define LGK_BARRIER() asm volatile("s_waitcnt lgkmcnt(0)\n\ts_barrier" ::: "memory")

__global__ __launch_bounds__(256) void build_w(
    const float* __restrict__ osc,     // [6][256][256]  osc[f][h][n]
    const float* __restrict__ t,       // [8][1]
    const float* __restrict__ phase,   // [6][256]       phase[f][n]
    __hip_bfloat16* __restrict__ Wt)   // [8][256][256]  Wt[b][n][h]
{
    const float freqs[6] = {1.f, 2.f, 4.f, 8.f, 7.f, 5.f};
    __shared__ float tr[16 * 68];      // [hlocal][n], stride 68

    const int b  = blockIdx.z;
    const int n0 = blockIdx.y * 64;    // 4 n-tiles
    const int h0 = blockIdx.x * 16;    // 16 h-slices
    const int tid = threadIdx.x;

    const float tb = t[b];
    const int nr = (tid & 15) * 4;
    const int hr = tid >> 4;           // 0..15
    float s[6][4];
#pragma unroll
    for (int f = 0; f < 6; ++f)
#pragma unroll
        for (int j = 0; j < 4; ++j)
            s[f][j] = __sinf(freqs[f] * tb + phase[f * 256 + n0 + nr + j]);

    const int h = h0 + hr;
    float4 acc = make_float4(0.f, 0.f, 0.f, 0.f);
#pragma unroll
    for (int f = 0; f < 6; ++f) {
        float4 o = *(const float4*)&osc[f * 65536 + h * 256 + n0 + nr];
        acc.x += o.x * s[f][0];
        acc.y += o.y * s[f][1];
        acc.z += o.z * s[f][2];
        acc.w += o.w * s[f][3];
    }
    *(float4*)&tr[hr * 68 + nr] = acc;
    __syncthreads();

    const int nw = tid >> 2;           // 0..63
    const int hw = (tid & 3) * 4;      // 0,4,8,12
    float v0 = tr[(hw + 0) * 68 + nw];
    float v1 = tr[(hw + 1) * 68 + nw];
    float v2 = tr[(hw + 2) * 68 + nw];
    float v3 = tr[(hw + 3) * 68 + nw];
    union { __hip_bfloat162 h2[2]; unsigned long long q; } cv;
    cv.h2[0] = __float22bfloat162_rn(make_float2(v0, v1));
    cv.h2[1] = __float22bfloat162_rn(make_float2(v2, v3));
    *(unsigned long long*)(Wt + (size_t)b * 65536 + (size_t)(n0 + nw) * 256 + h0 + hw) = cv.q;
}

// BK=64: LDS row stride 72 shorts (144 B), aliasing class measured clean (R6).
#define LDST 72

__global__ __launch_bounds__(512, 4) void gemm(
    const float* __restrict__ X,              // [8][4096][256] fp32
    const __hip_bfloat16* __restrict__ Wt,    // [8][256][256]  bf16 [b][n][h]
    float* __restrict__ out)                  // [8][4096][256] fp32
{
    __shared__ short As[64 * LDST];           // As[m][k]   9.2 KB
    __shared__ short Bs[256 * LDST];          // Bs[n][k]  36.9 KB (46 KB -> 2 blk/CU)

    const int b     = blockIdx.y;
    const int mTile = blockIdx.x;             // 0..63, BM=64, BN=256

    const int tid    = threadIdx.x;
    const int lane   = tid & 63;
    const int wave   = tid >> 6;              // 0..7
    const int lane15 = lane & 15;
    const int quad   = lane >> 4;             // 0..3
    const int wm     = wave >> 2;             // 0..1: 32-row band
    const int wn     = wave & 3;              // 0..3: 64-col band

    const float* Xb          = X   + (size_t)b * N_ * H_ + (size_t)mTile * 64 * H_;
    const __hip_bfloat16* Wb = Wt  + (size_t)b * H_ * H_;
    float* Ob                = out + (size_t)b * N_ * H_ + (size_t)mTile * 64 * H_;

    // A staging: 64 rows x 64 k fp32 = 16 KB -> 8 floats/thread (32 B contig)
    const int arow = tid >> 3;                // 0..63
    const int aseg = (tid & 7) * 8;           // 0,8,..,56
    const float* pa = Xb + (size_t)arow * H_ + aseg;

    // B staging: 256 rows x 64 k bf16 = 32 KB -> 32 shorts/thread (64 B contig)
    const int brow = tid >> 1;                // 0..255
    const int bhf  = (tid & 1) * 32;          // 0, 32
    const __hip_bfloat16* pb = Wb + (size_t)brow * H_ + bhf;

    f4v acc[2][4] = {};

    // depth-2 register prefetch: slots 0/1 hold iters it, it+1
    float4 a0[2], a1[2];
    uint4  bv[2][4];
#pragma unroll
    for (int sl = 0; sl < 2; ++sl) {
        const int k = sl * 64;
        a0[sl] = *(const float4*)(pa + k);
        a1[sl] = *(const float4*)(pa + k + 4);
#pragma unroll
        for (int j = 0; j < 4; ++j)
            bv[sl][j] = *(const uint4*)(pb + k + j * 8);
    }

    for (int it = 0; it < 4; ++it) {
        const int sl = it & 1;
        // stage slot sl -> LDS (A converted fp32->bf16 in-register)
        union { __hip_bfloat162 h2[4]; uint4 q; } cv;
        cv.h2[0] = __float22bfloat162_rn(make_float2(a0[sl].x, a0[sl].y));
        cv.h2[1] = __float22bfloat162_rn(make_float2(a0[sl].z, a0[sl].w));
        cv.h2[2] = __float22bfloat162_rn(make_float2(a1[sl].x, a1[sl].y));
        cv.h2[3] = __float22bfloat162_rn(make_float2(a1[sl].z, a1[sl].w));
        *(uint4*)(&As[arow * LDST + aseg]) = cv.q;
        *(uint4*)(&Bs[brow * LDST + bhf + 0])  = bv[sl][0];
        *(uint4*)(&Bs[brow * LDST + bhf + 8])  = bv[sl][1];
        *(uint4*)(&Bs[brow * LDST + bhf + 16]) = bv[sl][2];
        *(uint4*)(&Bs[brow * LDST + bhf + 24]) = bv[sl][3];
        LGK_BARRIER();                        // lgkmcnt only: prefetch stays in flight

        // prefetch iter it+2 into slot sl (overlaps MFMA; survives barriers)
        if (it < 2) {
            const int k = (it + 2) * 64;
            a0[sl] = *(const float4*)(pa + k);
            a1[sl] = *(const float4*)(pa + k + 4);
#pragma unroll
            for (int j = 0; j < 4; ++j)
                bv[sl][j] = *(const uint4*)(pb + k + j * 8);
        }

        // two k-halves per iter: frag k = kh*32 + quad*8 + j
#pragma unroll
        for (int kh = 0; kh < 2; ++kh) {
            s8v af[2], bf[4];
#pragma unroll
            for (int mt = 0; mt < 2; ++mt)
                af[mt] = *(const s8v*)(&As[(wm * 32 + mt * 16 + lane15) * LDST + kh * 32 + quad * 8]);
#pragma unroll
            for (int nt = 0; nt < 4; ++nt)
                bf[nt] = *(const s8v*)(&Bs[(wn * 64 + nt * 16 + lane15) * LDST + kh * 32 + quad * 8]);
#pragma unroll
            for (int mt = 0; mt < 2; ++mt)
#pragma unroll
                for (int nt = 0; nt < 4; ++nt)
                    acc[mt][nt] = __builtin_amdgcn_mfma_f32_16x16x32_bf16(
                        af[mt], bf[nt], acc[mt][nt], 0, 0, 0);
        }
        LGK_BARRIER();                        // reads retired; next staging may overwrite
    }

    // epilogue: C/D layout col=lane15, row=quad*4+reg; nontemporal (write-once)
#pragma unroll
    for (int mt = 0; mt < 2; ++mt) {
#pragma unroll
        for (int r = 0; r < 4; ++r) {
            int row = wm * 32 + mt * 16 + quad * 4 + r;
            float* po = Ob + (size_t)row * H_ + wn * 64 + lane15;
#pragma unroll
            for (int nt = 0; nt < 4; ++nt)
                __builtin_nontemporal_store(acc[mt][nt][r], po + nt * 16);
        }
    }
}

extern "C" void kernel_launch(void* const* d_in, const int* in_sizes, int n_in,
                              void* d_out, int out_size, void* d_ws, size_t ws_size,
                              hipStream_t stream) {
    const float* x     = (const float*)d_in[0];   // [8][4096][256]
    const float* t     = (const float*)d_in[1];   // [8][1]
    const float* osc   = (const float*)d_in[2];   // [6][256][256]
    const float* phase = (const float*)d_in[3];   // [6][256]
    __hip_bfloat16* Wt = (__hip_bfloat16*)d_ws;   // 1 MB scratch, rebuilt every call
    float* out = (float*)d_out;

    dim3 gw(16, 4, 8);                            // (h-slice, n-tile, b) = 512 blocks
    build_w<<<gw, 256, 0, stream>>>(osc, t, phase, Wt);

    dim3 gg(64, 8);                               // (mTile, b) = 512 blocks
    gemm<<<gg, 512, 0, stream>>>(x, Wt, out);
}